// Round 1
// baseline (75.755 us; speedup 1.0000x reference)
//
#include <hip/hip_runtime.h>

#define HW 16384
#define NB 4

// ws layout (floats):
// [0,4096)      Wk combined  [d][c]
// [4096,8192)   Wq combined  [d][c]
// [8192,8320)   bias (bk 64 | bq 64)
// [8320, +B*HW*64)          keys   [b][n][d]
// [8320+B*HW*64, +B*HW*64)  queries[b][n][d]
#define WS_BIAS 8192
#define WS_KEYS 8320
#define WS_QUER (8320 + NB * HW * 64)

// ---------------- Kernel A: fold the three linear layers ----------------
__global__ __launch_bounds__(256) void combine_weights(
    const float* __restrict__ conv_w, const float* __restrict__ conv_b,
    const float* __restrict__ key_w, const float* __restrict__ key_b,
    const float* __restrict__ query_w, const float* __restrict__ query_b,
    float* __restrict__ ws) {
    __shared__ float kw[4096], qw[4096], cw[4096], cb[64];
    int t = threadIdx.x;
    for (int i = t; i < 4096; i += 256) {
        kw[i] = key_w[i];
        qw[i] = query_w[i];
        cw[i] = conv_w[i];
    }
    if (t < 64) cb[t] = conv_b[t];
    __syncthreads();
    int base = blockIdx.x * 512;
    #pragma unroll
    for (int r = 0; r < 2; ++r) {
        int e = base + r * 256 + t;             // e in [0, 8192)
        int sel = e >> 12, rem = e & 4095;
        int d = rem >> 6, c = rem & 63;
        const float* Wm = sel ? qw : kw;
        float acc = 0.f;
        #pragma unroll 8
        for (int k = 0; k < 64; ++k) acc += Wm[d * 64 + k] * cw[k * 64 + c];
        ws[e] = acc;
    }
    if (blockIdx.x == 0 && t < 128) {
        int sel = t >> 6, d = t & 63;
        const float* Wm = sel ? qw : kw;
        float acc = 0.f;
        for (int k = 0; k < 64; ++k) acc += Wm[d * 64 + k] * cb[k];
        acc += sel ? query_b[d] : key_b[d];
        ws[WS_BIAS + t] = acc;
    }
}

// ---------------- Kernel B: keys/queries GEMM  [128][64] x [64][n] ----------------
__global__ __launch_bounds__(256) void gemm_kq(
    const float* __restrict__ x, const float* __restrict__ ws,
    float* __restrict__ keys, float* __restrict__ queries) {
    __shared__ float Wt[64][132];   // Wt[c][dall], dall in [0,128)
    __shared__ float xs[64][68];    // xs[node][c]
    __shared__ float bias[128];
    int t = threadIdx.x;
    int blk = blockIdx.x;
    int b = blk >> 8;
    int n0 = (blk & 255) << 6;

    for (int i = t; i < 8192; i += 256) Wt[i & 63][i >> 6] = ws[i];
    if (t < 128) bias[t] = ws[WS_BIAS + t];
    {
        int i = t & 63, cbase = (t >> 6) * 16;
        const float* xb = x + ((size_t)(b * 64 + cbase)) * HW + n0 + i;
        float v[16];
        #pragma unroll
        for (int k = 0; k < 16; ++k) v[k] = xb[(size_t)k * HW];
        #pragma unroll
        for (int q = 0; q < 4; ++q)
            *(float4*)&xs[i][cbase + q * 4] =
                make_float4(v[q * 4], v[q * 4 + 1], v[q * 4 + 2], v[q * 4 + 3]);
    }
    __syncthreads();

    int tn8 = t & 7, td = t >> 3;   // td in [0,32): dall base = td*4
    float acc[8][4];
    #pragma unroll
    for (int j = 0; j < 8; ++j)
        #pragma unroll
        for (int dd = 0; dd < 4; ++dd) acc[j][dd] = 0.f;

    #pragma unroll
    for (int c0 = 0; c0 < 64; c0 += 4) {
        float4 wv[4];
        #pragma unroll
        for (int q = 0; q < 4; ++q) wv[q] = *(const float4*)&Wt[c0 + q][td * 4];
        #pragma unroll
        for (int j = 0; j < 8; ++j) {
            float4 xv = *(const float4*)&xs[8 * j + tn8][c0];
            acc[j][0] += xv.x * wv[0].x + xv.y * wv[1].x + xv.z * wv[2].x + xv.w * wv[3].x;
            acc[j][1] += xv.x * wv[0].y + xv.y * wv[1].y + xv.z * wv[2].y + xv.w * wv[3].y;
            acc[j][2] += xv.x * wv[0].z + xv.y * wv[1].z + xv.z * wv[2].z + xv.w * wv[3].z;
            acc[j][3] += xv.x * wv[0].w + xv.y * wv[1].w + xv.z * wv[2].w + xv.w * wv[3].w;
        }
    }

    float* dst = (td < 16) ? keys : queries;
    int dof = (td < 16) ? td * 4 : (td - 16) * 4;
    float b0 = bias[td * 4 + 0], b1 = bias[td * 4 + 1];
    float b2 = bias[td * 4 + 2], b3 = bias[td * 4 + 3];
    #pragma unroll
    for (int j = 0; j < 8; ++j) {
        int n = n0 + 8 * j + tn8;
        *(float4*)&dst[((size_t)(b * HW + n)) * 64 + dof] =
            make_float4(acc[j][0] + b0, acc[j][1] + b1, acc[j][2] + b2, acc[j][3] + b3);
    }
}

// ---------------- Kernel C: gather + per-sample dot ----------------
__global__ __launch_bounds__(256) void affinity(
    const float* __restrict__ keys, const float* __restrict__ queries,
    const int* __restrict__ rnd, float* __restrict__ out) {
    __shared__ float qs[8][68];
    __shared__ float res[208];
    int t = threadIdx.x;
    int blk = blockIdx.x;
    int b = blk >> 11;
    int n0 = (blk & 2047) << 3;

    for (int idx = t; idx < 512; idx += 256)
        qs[idx >> 6][idx & 63] = queries[((size_t)(b * HW + n0) << 6) + idx];
    __syncthreads();

    int j = t & 3;         // lane in 4-lane group
    int g = t >> 2;        // group id within block [0,64)
    #pragma unroll
    for (int it = 0; it < 4; ++it) {
        int p = it * 64 + g;
        if (p < 208) {
            int n_loc = p / 26;
            int s = p - n_loc * 26;
            int n = n0 + n_loc;
            int idxn;
            if (s < 25) {
                int y = n >> 7, xq = n & 127;
                int dy = s / 5 - 2, dx = s - (s / 5) * 5 - 2;
                int ry = y + dy;
                ry = ry < 0 ? -ry : (ry > 127 ? 254 - ry : ry);
                int rx = xq + dx;
                rx = rx < 0 ? -rx : (rx > 127 ? 254 - rx : rx);
                idxn = (ry << 7) + rx;
            } else {
                idxn = rnd[b * HW + n];
            }
            const float4* kp = (const float4*)(keys + (((size_t)(b * HW + idxn)) << 6) + j * 16);
            float acc = 0.f;
            #pragma unroll
            for (int m = 0; m < 4; ++m) {
                float4 kv = kp[m];
                float4 qv = *(const float4*)&qs[n_loc][j * 16 + m * 4];
                acc += kv.x * qv.x + kv.y * qv.y + kv.z * qv.z + kv.w * qv.w;
            }
            acc += __shfl_xor(acc, 1);
            acc += __shfl_xor(acc, 2);
            if (j == 0) res[p] = acc * 0.125f;   // C^-0.5 = 1/8
        }
    }
    __syncthreads();
    if (t < 208) out[((size_t)(b * HW + n0)) * 26 + t] = res[t];
}

extern "C" void kernel_launch(void* const* d_in, const int* in_sizes, int n_in,
                              void* d_out, int out_size, void* d_ws, size_t ws_size,
                              hipStream_t stream) {
    const float* x       = (const float*)d_in[0];
    const float* conv_w  = (const float*)d_in[1];
    const float* conv_b  = (const float*)d_in[2];
    const float* key_w   = (const float*)d_in[3];
    const float* key_b   = (const float*)d_in[4];
    const float* query_w = (const float*)d_in[5];
    const float* query_b = (const float*)d_in[6];
    const int*   rnd     = (const int*)d_in[7];
    float* ws  = (float*)d_ws;
    float* out = (float*)d_out;

    float* keys = ws + WS_KEYS;
    float* quer = ws + WS_QUER;

    combine_weights<<<16, 256, 0, stream>>>(conv_w, conv_b, key_w, key_b,
                                            query_w, query_b, ws);
    gemm_kq<<<NB * (HW / 64), 256, 0, stream>>>(x, ws, keys, quer);
    affinity<<<NB * (HW / 8), 256, 0, stream>>>(keys, quer, rnd, out);
}

// Round 2
// 65.991 us; speedup vs baseline: 1.1480x; 1.1480x over previous
//
#include <hip/hip_runtime.h>

#define HW 16384
#define NB 4

// ws layout (floats):
// [0,8192)      combined W: [sel(2)][d(64)][c(64)]  (sel 0=keys, 1=queries)
// [8192,8320)   combined bias (bk 64 | bq 64)
// [8320, +B*HW*64)          keys   [b][n][d]
// [8320+B*HW*64, +B*HW*64)  queries[b][n][d]
#define WS_BIAS 8192
#define WS_KEYS 8320
#define WS_QUER (8320 + NB * HW * 64)

// ---------------- Kernel A: fold the three linear layers ----------------
// 32 blocks: sel = bx>>4, d-rows d0..d0+3. Each thread -> one W element.
__global__ __launch_bounds__(256) void combine_weights(
    const float* __restrict__ conv_w, const float* __restrict__ conv_b,
    const float* __restrict__ key_w, const float* __restrict__ key_b,
    const float* __restrict__ query_w, const float* __restrict__ query_b,
    float* __restrict__ ws) {
    __shared__ float cw[4096];    // conv_w [d][c]
    __shared__ float wr[4][64];   // 4 rows of key_w or query_w
    __shared__ float cb[64];
    int t = threadIdx.x;
    int bx = blockIdx.x;
    int sel = bx >> 4, d0 = (bx & 15) * 4;
    const float* Wm = sel ? query_w : key_w;
    for (int i = t; i < 4096; i += 256) cw[i] = conv_w[i];
    wr[t >> 6][t & 63] = Wm[d0 * 64 + t];   // rows d0..d0+3, k = t&63
    if (t < 64) cb[t] = conv_b[t];
    __syncthreads();
    int dd = t >> 6, c = t & 63;
    float acc = 0.f;
    #pragma unroll 8
    for (int k = 0; k < 64; ++k) acc += wr[dd][k] * cw[k * 64 + c];
    ws[(sel * 64 + d0 + dd) * 64 + c] = acc;
    if (t < 4) {
        float bacc = 0.f;
        for (int k = 0; k < 64; ++k) bacc += wr[t][k] * cb[k];
        bacc += (sel ? query_b : key_b)[d0 + t];
        ws[WS_BIAS + sel * 64 + d0 + t] = bacc;
    }
}

// ---------------- Kernel B: keys/queries GEMM  [128 d][64 c] x [64 c][n] ----------------
// 128-node tiles, 8n x 8d per thread, 2 blocks/CU.
__global__ __launch_bounds__(256, 2) void gemm_kq(
    const float* __restrict__ x, const float* __restrict__ ws,
    float* __restrict__ keys, float* __restrict__ queries) {
    __shared__ float Wt[64][132];   // Wt[c][dall], dall in [0,128)
    __shared__ float xs[128][68];   // xs[node][c]
    __shared__ float bias[128];
    int t = threadIdx.x;
    int blk = blockIdx.x;
    int b = blk >> 7;
    int n0 = (blk & 127) << 7;

    for (int i = t; i < 8192; i += 256) Wt[i & 63][i >> 6] = ws[i];
    if (t < 128) bias[t] = ws[WS_BIAS + t];
    {
        int n = t & 127;             // lanes cover consecutive n -> coalesced
        int cb = (t >> 7) * 32;      // c chunk: 0 or 32
        const float* xp = x + ((size_t)(b * 64 + cb)) * HW + n0 + n;
        float v[32];
        #pragma unroll
        for (int k = 0; k < 32; ++k) v[k] = xp[(size_t)k * HW];
        #pragma unroll
        for (int q = 0; q < 8; ++q)
            *(float4*)&xs[n][cb + q * 4] =
                make_float4(v[4 * q], v[4 * q + 1], v[4 * q + 2], v[4 * q + 3]);
    }
    __syncthreads();

    int ng = t & 15;   // n rows: ng + 16*j  (16 rows/wave, 2-way LDS alias = free)
    int dg = t >> 4;   // d block: dg*8 .. dg*8+7
    float acc[8][8];
    #pragma unroll
    for (int j = 0; j < 8; ++j)
        #pragma unroll
        for (int d = 0; d < 8; ++d) acc[j][d] = 0.f;

    #pragma unroll 4
    for (int c0 = 0; c0 < 64; c0 += 4) {
        float4 xv[8];
        #pragma unroll
        for (int j = 0; j < 8; ++j) xv[j] = *(const float4*)&xs[ng + 16 * j][c0];
        float4 w0[4], w1[4];
        #pragma unroll
        for (int q = 0; q < 4; ++q) {
            w0[q] = *(const float4*)&Wt[c0 + q][dg * 8];
            w1[q] = *(const float4*)&Wt[c0 + q][dg * 8 + 4];
        }
        #pragma unroll
        for (int j = 0; j < 8; ++j) {
            #pragma unroll
            for (int q = 0; q < 4; ++q) {
                float xc = q == 0 ? xv[j].x : q == 1 ? xv[j].y : q == 2 ? xv[j].z : xv[j].w;
                acc[j][0] += xc * w0[q].x; acc[j][1] += xc * w0[q].y;
                acc[j][2] += xc * w0[q].z; acc[j][3] += xc * w0[q].w;
                acc[j][4] += xc * w1[q].x; acc[j][5] += xc * w1[q].y;
                acc[j][6] += xc * w1[q].z; acc[j][7] += xc * w1[q].w;
            }
        }
    }

    float* dst = (dg < 8) ? keys : queries;
    int dof = (dg & 7) * 8;
    float b0 = bias[dg * 8 + 0], b1 = bias[dg * 8 + 1], b2 = bias[dg * 8 + 2], b3 = bias[dg * 8 + 3];
    float b4 = bias[dg * 8 + 4], b5 = bias[dg * 8 + 5], b6 = bias[dg * 8 + 6], b7 = bias[dg * 8 + 7];
    #pragma unroll
    for (int j = 0; j < 8; ++j) {
        int n = n0 + ng + 16 * j;
        float* dp = &dst[((size_t)(b * HW + n)) * 64 + dof];
        *(float4*)dp       = make_float4(acc[j][0] + b0, acc[j][1] + b1, acc[j][2] + b2, acc[j][3] + b3);
        *(float4*)(dp + 4) = make_float4(acc[j][4] + b4, acc[j][5] + b5, acc[j][6] + b6, acc[j][7] + b7);
    }
}

// ---------------- Kernel C: gather + per-sample dot ----------------
// 16 nodes/block; group = 4 lanes, fixed (node, sample-phase); query slice in regs.
__global__ __launch_bounds__(256) void affinity(
    const float* __restrict__ keys, const float* __restrict__ queries,
    const int* __restrict__ rnd, float* __restrict__ out) {
    __shared__ float res[416];
    int t = threadIdx.x;
    int blk = blockIdx.x;
    int b = blk >> 10;
    int n0 = (blk & 1023) << 4;

    int j = t & 3;          // d slice j*16 .. j*16+15
    int g = t >> 2;         // 64 groups
    int n_loc = g >> 2;     // 16 nodes x 4 groups
    int sb = g & 3;         // sample phase: s = sb + 4k
    int n = n0 + n_loc;

    const float4* qp = (const float4*)(queries + ((size_t)(b * HW + n)) * 64 + j * 16);
    float4 qv0 = qp[0], qv1 = qp[1], qv2 = qp[2], qv3 = qp[3];

    int y = n >> 7, xq = n & 127;
    const float* kbase = keys + (((size_t)b * HW) << 6) + j * 16;

    #pragma unroll
    for (int k = 0; k < 7; ++k) {
        int s = sb + 4 * k;
        if (s < 26) {
            int idxn;
            if (s < 25) {
                int q5 = s / 5;
                int dy = q5 - 2, dx = s - q5 * 5 - 2;
                int ry = y + dy;
                ry = ry < 0 ? -ry : (ry > 127 ? 254 - ry : ry);
                int rx = xq + dx;
                rx = rx < 0 ? -rx : (rx > 127 ? 254 - rx : rx);
                idxn = (ry << 7) + rx;
            } else {
                idxn = rnd[b * HW + n];
            }
            const float4* kp = (const float4*)(kbase + ((size_t)idxn << 6));
            float4 k0 = kp[0], k1 = kp[1], k2 = kp[2], k3 = kp[3];
            float a = k0.x * qv0.x + k0.y * qv0.y + k0.z * qv0.z + k0.w * qv0.w
                    + k1.x * qv1.x + k1.y * qv1.y + k1.z * qv1.z + k1.w * qv1.w
                    + k2.x * qv2.x + k2.y * qv2.y + k2.z * qv2.z + k2.w * qv2.w
                    + k3.x * qv3.x + k3.y * qv3.y + k3.z * qv3.z + k3.w * qv3.w;
            a += __shfl_xor(a, 1);
            a += __shfl_xor(a, 2);
            if (j == 0) res[n_loc * 26 + s] = a * 0.125f;   // C^-0.5 = 1/8
        }
    }
    __syncthreads();
    size_t ob = ((size_t)(b * HW + n0)) * 26;
    out[ob + t] = res[t];
    if (t < 160) out[ob + 256 + t] = res[256 + t];
}

extern "C" void kernel_launch(void* const* d_in, const int* in_sizes, int n_in,
                              void* d_out, int out_size, void* d_ws, size_t ws_size,
                              hipStream_t stream) {
    const float* x       = (const float*)d_in[0];
    const float* conv_w  = (const float*)d_in[1];
    const float* conv_b  = (const float*)d_in[2];
    const float* key_w   = (const float*)d_in[3];
    const float* key_b   = (const float*)d_in[4];
    const float* query_w = (const float*)d_in[5];
    const float* query_b = (const float*)d_in[6];
    const int*   rnd     = (const int*)d_in[7];
    float* ws  = (float*)d_ws;
    float* out = (float*)d_out;

    float* keys = ws + WS_KEYS;
    float* quer = ws + WS_QUER;

    combine_weights<<<32, 256, 0, stream>>>(conv_w, conv_b, key_w, key_b,
                                            query_w, query_b, ws);
    gemm_kq<<<NB * (HW / 128), 256, 0, stream>>>(x, ws, keys, quer);
    affinity<<<NB * (HW / 16), 256, 0, stream>>>(keys, quer, rnd, out);
}

// Round 3
// 37.112 us; speedup vs baseline: 2.0413x; 1.7782x over previous
//
#include <hip/hip_runtime.h>
#include <hip/hip_bf16.h>

#define HW 16384
#define NB 4

typedef __attribute__((ext_vector_type(8))) short bf16x8;
typedef __attribute__((ext_vector_type(4))) float f32x4;

__device__ __forceinline__ float blo(unsigned u) { return __uint_as_float(u << 16); }
__device__ __forceinline__ float bhi(unsigned u) { return __uint_as_float(u & 0xffff0000u); }

// ws byte layout:
// [0,16384)          Wbf16 [2][64 d][64 c] ushort  (sel 0=keys, 1=queries)
// [16384,16896)      combined bias f32 [128]
// [32768,+8.4MB)     keys    bf16 [4][16384][64]
// [.. ,+8.4MB)       queries bf16 [4][16384][64]

// ---------------- Kernel A: fold the three linear layers -> bf16 W ----------------
__global__ __launch_bounds__(256) void combine_weights(
    const float* __restrict__ conv_w, const float* __restrict__ conv_b,
    const float* __restrict__ key_w, const float* __restrict__ key_b,
    const float* __restrict__ query_w, const float* __restrict__ query_b,
    ushort* __restrict__ Wb, float* __restrict__ bout) {
    __shared__ float cw[4096];
    __shared__ float wr[4][64];
    __shared__ float cb[64];
    int t = threadIdx.x, bx = blockIdx.x;
    int sel = bx >> 4, d0 = (bx & 15) * 4;
    const float* Wm = sel ? query_w : key_w;
    for (int i = t; i < 4096; i += 256) cw[i] = conv_w[i];
    wr[t >> 6][t & 63] = Wm[d0 * 64 + t];
    if (t < 64) cb[t] = conv_b[t];
    __syncthreads();
    int dd = t >> 6, c = t & 63;
    float acc = 0.f;
    #pragma unroll 8
    for (int k = 0; k < 64; ++k) acc += wr[dd][k] * cw[k * 64 + c];
    __hip_bfloat16 h = __float2bfloat16(acc);
    Wb[(sel * 64 + d0 + dd) * 64 + c] = *(ushort*)&h;
    if (t < 4) {
        float bacc = 0.f;
        for (int k = 0; k < 64; ++k) bacc += wr[t][k] * cb[k];
        bacc += (sel ? query_b : key_b)[d0 + t];
        bout[sel * 64 + d0 + t] = bacc;
    }
}

// ---------------- Kernel B: MFMA GEMM  keys/queries = W[128][64] x x[64][n] ----------------
// 256-node tiles, 4 waves x (64 n x 128 d), K=64 in one shot (2 mfma per tile).
__global__ __launch_bounds__(256, 2) void gemm_kq(
    const float* __restrict__ x, const ushort* __restrict__ W,
    const float* __restrict__ bias, ushort* __restrict__ keys,
    ushort* __restrict__ queries) {
    __shared__ ushort xs[256 * 64];   // [n][c] bf16, 16B-chunk XOR swizzle
    __shared__ ushort epi[256 * 64];  // [n][64 d] bf16 per phase
    __shared__ float bs[128];
    int t = threadIdx.x;
    int b = blockIdx.x >> 6;
    int n0 = (blockIdx.x & 63) << 8;

    if (t < 128) bs[t] = bias[t];
    {   // stage x: thread t -> node n0+t, all 64 channels, convert to bf16
        const float* xp = x + ((size_t)b << 20) + n0 + t;
        unsigned u[32];
        #pragma unroll
        for (int cc = 0; cc < 32; ++cc) {
            float lo = xp[(size_t)(2 * cc) * HW];
            float hi = xp[(size_t)(2 * cc + 1) * HW];
            __hip_bfloat162 h2 = __float22bfloat162_rn(make_float2(lo, hi));
            u[cc] = *(unsigned*)&h2;
        }
        #pragma unroll
        for (int q = 0; q < 8; ++q)
            *(uint4*)((char*)xs + t * 128 + (((q ^ (t & 7))) << 4)) =
                make_uint4(u[4 * q], u[4 * q + 1], u[4 * q + 2], u[4 * q + 3]);
    }
    __syncthreads();

    int l = t & 63, w = t >> 6;
    int ncol = l & 15, kg = l >> 4;           // MFMA lane coords

    bf16x8 Bf[4][2];                          // [nt][k-half]
    #pragma unroll
    for (int nt = 0; nt < 4; ++nt) {
        int row = w * 64 + nt * 16 + ncol;
        #pragma unroll
        for (int half = 0; half < 2; ++half) {
            int q = half * 4 + kg;
            Bf[nt][half] = *(bf16x8*)((char*)xs + row * 128 + ((q ^ (row & 7)) << 4));
        }
    }

    f32x4 acc[8][4];                          // [dt][nt]
    #pragma unroll
    for (int dt = 0; dt < 8; ++dt)
        #pragma unroll
        for (int nt = 0; nt < 4; ++nt) acc[dt][nt] = (f32x4){0.f, 0.f, 0.f, 0.f};

    #pragma unroll
    for (int dt = 0; dt < 8; ++dt) {
        const bf16x8* arow = (const bf16x8*)(W + (dt * 16 + ncol) * 64 + kg * 8);
        bf16x8 A0 = arow[0];     // c = kg*8 .. +7
        bf16x8 A1 = arow[4];     // c = 32 + kg*8 .. +7
        #pragma unroll
        for (int nt = 0; nt < 4; ++nt) {
            acc[dt][nt] = __builtin_amdgcn_mfma_f32_16x16x32_bf16(A0, Bf[nt][0], acc[dt][nt], 0, 0, 0);
            acc[dt][nt] = __builtin_amdgcn_mfma_f32_16x16x32_bf16(A1, Bf[nt][1], acc[dt][nt], 0, 0, 0);
        }
    }

    // epilogue: phase 0 = keys (d 0..63), phase 1 = queries (d 64..127)
    #pragma unroll
    for (int p = 0; p < 2; ++p) {
        #pragma unroll
        for (int dt = 0; dt < 4; ++dt) {
            int dbase = dt * 16 + kg * 4;     // d within 64-wide half
            float4 bb = *(float4*)&bs[p * 64 + dbase];
            #pragma unroll
            for (int nt = 0; nt < 4; ++nt) {
                int n = w * 64 + nt * 16 + ncol;
                f32x4 a = acc[p * 4 + dt][nt];
                __hip_bfloat162 lo2 = __float22bfloat162_rn(make_float2(a[0] + bb.x, a[1] + bb.y));
                __hip_bfloat162 hi2 = __float22bfloat162_rn(make_float2(a[2] + bb.z, a[3] + bb.w));
                *(uint2*)((char*)epi + n * 128 + (((dbase >> 3) ^ (n & 7)) << 4) + ((dbase & 4) << 1)) =
                    make_uint2(*(unsigned*)&lo2, *(unsigned*)&hi2);
            }
        }
        __syncthreads();
        ushort* dst = p ? queries : keys;
        #pragma unroll
        for (int i = 0; i < 8; ++i) {
            int idx = i * 256 + t;
            int row = idx >> 3, ch = idx & 7;
            uint4 v = *(uint4*)((char*)epi + row * 128 + ((ch ^ (row & 7)) << 4));
            *(uint4*)(dst + (((size_t)(b * HW + n0 + row)) << 6) + ch * 8) = v;
        }
        __syncthreads();
    }
}

// ---------------- Kernel C: gather + per-sample dot (bf16 keys/queries) ----------------
__global__ __launch_bounds__(256) void affinity(
    const ushort* __restrict__ keys, const ushort* __restrict__ queries,
    const int* __restrict__ rnd, float* __restrict__ out) {
    __shared__ float res[416];
    int t = threadIdx.x;
    int b = blockIdx.x >> 10;
    int n0 = (blockIdx.x & 1023) << 4;

    int j = t & 3;           // d slice j*16 .. +15
    int g = t >> 2;
    int n_loc = g & 15;      // 16 consecutive nodes across lanes -> coalesced gathers
    int sb = g >> 4;         // sample phase: s = sb + 4k
    int n = n0 + n_loc;

    const uint4* qp = (const uint4*)(queries + (((size_t)(b * HW + n)) << 6) + j * 16);
    uint4 qa = qp[0], qb = qp[1];
    float qf[16];
    qf[0] = blo(qa.x); qf[1] = bhi(qa.x); qf[2] = blo(qa.y); qf[3] = bhi(qa.y);
    qf[4] = blo(qa.z); qf[5] = bhi(qa.z); qf[6] = blo(qa.w); qf[7] = bhi(qa.w);
    qf[8] = blo(qb.x); qf[9] = bhi(qb.x); qf[10] = blo(qb.y); qf[11] = bhi(qb.y);
    qf[12] = blo(qb.z); qf[13] = bhi(qb.z); qf[14] = blo(qb.w); qf[15] = bhi(qb.w);

    int y = n >> 7, xq = n & 127;
    const ushort* kb_ = keys + (((size_t)b * HW) << 6) + j * 16;
    int rix = rnd[b * HW + n];

    #pragma unroll
    for (int k = 0; k < 7; ++k) {
        int s = sb + 4 * k;
        if (s < 26) {
            int idxn;
            if (s < 25) {
                int q5 = s / 5;
                int dy = q5 - 2, dx = s - q5 * 5 - 2;
                int ry = y + dy;
                ry = ry < 0 ? -ry : (ry > 127 ? 254 - ry : ry);
                int rx = xq + dx;
                rx = rx < 0 ? -rx : (rx > 127 ? 254 - rx : rx);
                idxn = (ry << 7) + rx;
            } else {
                idxn = rix;
            }
            const uint4* kp = (const uint4*)(kb_ + ((size_t)idxn << 6));
            uint4 ka = kp[0], kc = kp[1];
            float a = 0.f;
            a = fmaf(blo(ka.x), qf[0], a);  a = fmaf(bhi(ka.x), qf[1], a);
            a = fmaf(blo(ka.y), qf[2], a);  a = fmaf(bhi(ka.y), qf[3], a);
            a = fmaf(blo(ka.z), qf[4], a);  a = fmaf(bhi(ka.z), qf[5], a);
            a = fmaf(blo(ka.w), qf[6], a);  a = fmaf(bhi(ka.w), qf[7], a);
            a = fmaf(blo(kc.x), qf[8], a);  a = fmaf(bhi(kc.x), qf[9], a);
            a = fmaf(blo(kc.y), qf[10], a); a = fmaf(bhi(kc.y), qf[11], a);
            a = fmaf(blo(kc.z), qf[12], a); a = fmaf(bhi(kc.z), qf[13], a);
            a = fmaf(blo(kc.w), qf[14], a); a = fmaf(bhi(kc.w), qf[15], a);
            a += __shfl_xor(a, 1);
            a += __shfl_xor(a, 2);
            if (j == 0) res[n_loc * 26 + s] = a * 0.125f;
        }
    }
    __syncthreads();
    size_t ob = ((size_t)(b * HW + n0)) * 26;
    out[ob + t] = res[t];
    if (t < 160) out[ob + 256 + t] = res[256 + t];
}

extern "C" void kernel_launch(void* const* d_in, const int* in_sizes, int n_in,
                              void* d_out, int out_size, void* d_ws, size_t ws_size,
                              hipStream_t stream) {
    const float* x       = (const float*)d_in[0];
    const float* conv_w  = (const float*)d_in[1];
    const float* conv_b  = (const float*)d_in[2];
    const float* key_w   = (const float*)d_in[3];
    const float* key_b   = (const float*)d_in[4];
    const float* query_w = (const float*)d_in[5];
    const float* query_b = (const float*)d_in[6];
    const int*   rnd     = (const int*)d_in[7];
    float* out = (float*)d_out;

    ushort* Wb    = (ushort*)d_ws;
    float*  biasp = (float*)((char*)d_ws + 16384);
    ushort* keys  = (ushort*)((char*)d_ws + 32768);
    ushort* quer  = keys + (size_t)NB * HW * 64;

    combine_weights<<<32, 256, 0, stream>>>(conv_w, conv_b, key_w, key_b,
                                            query_w, query_b, Wb, biasp);
    gemm_kq<<<NB * (HW / 256), 256, 0, stream>>>(x, Wb, biasp, keys, quer);
    affinity<<<NB * (HW / 16), 256, 0, stream>>>(keys, quer, rnd, out);
}